// Round 6
// baseline (320.958 us; speedup 1.0000x reference)
//
#include <hip/hip_runtime.h>

// Problem constants (fixed by the reference).
#define D      256        // vq_embed_dim == C
#define N_E    16384      // codebook size
#define NPTS   8192       // B*H*W
#define ZOUT   2097152    // elements of z_hat_out
#define MARGIN 2.0e-2f    // candidate window; bf16-hi GEMM d-error ~7 sigma
#define STRIPS 4          // 256-code strips per block

typedef short bf16x8 __attribute__((ext_vector_type(8)));
typedef unsigned short us8 __attribute__((ext_vector_type(8)));
typedef float f32x16 __attribute__((ext_vector_type(16)));
typedef unsigned long long u64;

__device__ __forceinline__ unsigned short f2bf(float x) {  // RNE
    unsigned int u = __float_as_uint(x);
    return (unsigned short)((u + 0x7FFFu + ((u >> 16) & 1u)) >> 16);
}
__device__ __forceinline__ void gl_lds16(const void* g, void* l) {
    __builtin_amdgcn_global_load_lds(
        (const __attribute__((address_space(1))) unsigned int*)g,
        (__attribute__((address_space(3))) unsigned int*)l, 16, 0, 0);
}

// ---------------------------------------------------------------------------
// Fused prep. Blocks [0,256): z (32 points each). Blocks [256,768): emb
// (32 codes each). Zpk = bf16(-2z), Epk = bf16(emb), both in MFMA fragment-
// chunk layout (chunk (g,ks): 64 lanes x 16B, lane l = (row&31)+((k>>3)&1)*32).
// Zf32 = z transposed to [n][k]. e2[j] = |emb_j|^2 fp32.
// ---------------------------------------------------------------------------
__global__ __launch_bounds__(256) void prep(
    const float* __restrict__ z, const float* __restrict__ emb,
    unsigned short* __restrict__ Zpk, float* __restrict__ Zf32,
    unsigned short* __restrict__ Epk, float* __restrict__ e2) {
    const int t = threadIdx.x;
    if (blockIdx.x < 256) {
        const int n0 = blockIdx.x * 32;
        const int p = t & 31, ks8 = t >> 5;     // 8 k-slabs of 32
        const int n = n0 + p;
        const int b = n >> 10, hw = n & 1023;
        const float* zb = z + (size_t)b * 262144 + hw;
        const int k0 = ks8 * 32;
        float v[32];
        #pragma unroll
        for (int kk = 0; kk < 32; ++kk)
            v[kk] = zb[(size_t)(k0 + kk) * 1024];   // coalesced in p
        #pragma unroll
        for (int i = 0; i < 8; ++i) {
            float4 f = {v[i * 4], v[i * 4 + 1], v[i * 4 + 2], v[i * 4 + 3]};
            *(float4*)(Zf32 + (size_t)n * D + k0 + i * 4) = f;
        }
        const int g = n >> 5;
        #pragma unroll
        for (int i = 0; i < 4; ++i) {               // 4 us8 per 32-k slab
            us8 hv;
            #pragma unroll
            for (int c = 0; c < 8; ++c) hv[c] = f2bf(-2.0f * v[i * 8 + c]);
            const int kabs = k0 + i * 8;
            const int ks = kabs >> 4;
            const int l = (n & 31) + ((kabs >> 3) & 1) * 32;
            *(us8*)(Zpk + ((size_t)(g * 16 + ks) * 64 + l) * 8) = hv;
        }
    } else {
        const int j0 = (blockIdx.x - 256) * 32;
        const int jj = j0 + (t >> 3), q = t & 7;    // 8 k-slabs of 32
        const float* row = emb + (size_t)jj * D + q * 32;
        float v[32];
        float s = 0.f;
        #pragma unroll
        for (int i = 0; i < 8; ++i) {
            const float4 x = *(const float4*)(row + i * 4);
            v[i * 4] = x.x; v[i * 4 + 1] = x.y; v[i * 4 + 2] = x.z; v[i * 4 + 3] = x.w;
            s += x.x * x.x + x.y * x.y + x.z * x.z + x.w * x.w;
        }
        const int g = jj >> 5;
        #pragma unroll
        for (int i = 0; i < 4; ++i) {
            us8 hv;
            #pragma unroll
            for (int c = 0; c < 8; ++c) hv[c] = f2bf(v[i * 8 + c]);
            const int kabs = q * 32 + i * 8;
            const int ks = kabs >> 4;
            const int l = (jj & 31) + ((kabs >> 3) & 1) * 32;
            *(us8*)(Epk + ((size_t)(g * 16 + ks) * 64 + l) * 8) = hv;
        }
        s += __shfl_xor(s, 1);
        s += __shfl_xor(s, 2);
        s += __shfl_xor(s, 4);
        if (q == 0) e2[jj] = s;
    }
}

// ---------------------------------------------------------------------------
// GEMM + group-min + candidate mask. Block: 128 points (LDS, staged once) x
// STRIPS*256 codes. 4 waves; wave wid owns a DISTINCT 64-code column, all 128
// points. Wave frags: 2 code x 4 point of 32x32x16; ef from global (fragment-
// contiguous chunks, DEPTH-2 register prefetch + cross-strip preload hidden
// under the epilogue), pf from LDS (depth-1). Plain dim3(64,16) grid — the
// natural dispatch already gives Z-tile L2 locality (readers share bx%8);
// round-5's manual XCD swizzle destroyed it (FETCH 37->462 MB). Do not swizzle.
// d~ = e2[code] + acc (Zpk holds -2z). Per (point, 64-code group) emits:
//   tminv[pt][g] = min over 64 codes
//   tmask[pt][g] = bitmask of codes with d~ <= min+MARGIN
// ---------------------------------------------------------------------------
__global__ __launch_bounds__(256, 2) void mfma_gemm(
    const unsigned short* __restrict__ Epk, const unsigned short* __restrict__ Zpk,
    const float* __restrict__ e2, float* __restrict__ tminv,
    u64* __restrict__ tmask) {
    __shared__ unsigned short Zbuf[64 * 512];   // 64 KB

    const int tid = threadIdx.x, lane = tid & 63, wid = tid >> 6;
    const int c32 = lane & 31, l5 = lane >> 5;
    const int n0 = blockIdx.x * 128;
    const int cs0 = blockIdx.y * (STRIPS * 256);

    #pragma unroll
    for (int ks = 0; ks < 16; ++ks)
        gl_lds16(Zpk + ((size_t)((n0 >> 5) + wid) * 16 + ks) * 512 + lane * 8,
                 Zbuf + (wid * 16 + ks) * 512);

    // Strip-0 E preload (depth-2 worth), overlapped with the Z staging.
    const unsigned short* ebase =
        Epk + ((size_t)((cs0 >> 5) + wid * 2) * 16) * 512 + lane * 8;
    bf16x8 ep0 = *(const bf16x8*)(ebase);
    bf16x8 ep1 = *(const bf16x8*)(ebase + 16 * 512);
    bf16x8 ep2 = *(const bf16x8*)(ebase + 512);
    bf16x8 ep3 = *(const bf16x8*)(ebase + 17 * 512);

    __syncthreads();   // single drain per block

    for (int s = 0; s < STRIPS; ++s) {
        const int cb = cs0 + s * 256 + wid * 64;   // this wave's 64 codes
        const unsigned short* eb = ebase + (size_t)s * 65536;  // 8 groups/strip
        const unsigned short* zb = Zbuf + lane * 8;

        f32x16 acc[2][4];
        const f32x16 z16 = {0.f};
        #pragma unroll
        for (int i = 0; i < 2; ++i)
            #pragma unroll
            for (int j = 0; j < 4; ++j) acc[i][j] = z16;

        // depth-2 E ring seeded by the preload; P depth-1 from LDS
        bf16x8 ec0 = ep0, ec1 = ep1;   // ks
        bf16x8 en0 = ep2, en1 = ep3;   // ks+1
        bf16x8 pc[4], pn[4];
        #pragma unroll
        for (int j = 0; j < 4; ++j) pc[j] = *(const bf16x8*)(zb + (j * 16) * 512);

        #pragma unroll
        for (int ks = 0; ks < 16; ++ks) {
            const bf16x8 ef0 = ec0, ef1 = ec1;
            ec0 = en0; ec1 = en1;
            if (ks < 14) {              // issue E for ks+2 (depth 2)
                en0 = *(const bf16x8*)(eb + (ks + 2) * 512);
                en1 = *(const bf16x8*)(eb + (16 + ks + 2) * 512);
            }
            if (ks < 15) {
                #pragma unroll
                for (int j = 0; j < 4; ++j)
                    pn[j] = *(const bf16x8*)(zb + (j * 16 + ks + 1) * 512);
            }
            acc[0][0] = __builtin_amdgcn_mfma_f32_32x32x16_bf16(ef0, pc[0], acc[0][0], 0, 0, 0);
            acc[0][1] = __builtin_amdgcn_mfma_f32_32x32x16_bf16(ef0, pc[1], acc[0][1], 0, 0, 0);
            acc[0][2] = __builtin_amdgcn_mfma_f32_32x32x16_bf16(ef0, pc[2], acc[0][2], 0, 0, 0);
            acc[0][3] = __builtin_amdgcn_mfma_f32_32x32x16_bf16(ef0, pc[3], acc[0][3], 0, 0, 0);
            acc[1][0] = __builtin_amdgcn_mfma_f32_32x32x16_bf16(ef1, pc[0], acc[1][0], 0, 0, 0);
            acc[1][1] = __builtin_amdgcn_mfma_f32_32x32x16_bf16(ef1, pc[1], acc[1][1], 0, 0, 0);
            acc[1][2] = __builtin_amdgcn_mfma_f32_32x32x16_bf16(ef1, pc[2], acc[1][2], 0, 0, 0);
            acc[1][3] = __builtin_amdgcn_mfma_f32_32x32x16_bf16(ef1, pc[3], acc[1][3], 0, 0, 0);
            if (ks < 15) {
                #pragma unroll
                for (int j = 0; j < 4; ++j) pc[j] = pn[j];
            }
        }

        // Next strip's first two E pairs: issue NOW so the long VALU epilogue
        // hides their latency (kills the strip cold-start stall).
        if (s < STRIPS - 1) {
            const unsigned short* ebn = eb + 65536;
            ep0 = *(const bf16x8*)(ebn);
            ep1 = *(const bf16x8*)(ebn + 16 * 512);
            ep2 = *(const bf16x8*)(ebn + 512);
            ep3 = *(const bf16x8*)(ebn + 17 * 512);
        }

        // Epilogue: per point-lane, min over the wave's 64 codes + candidate
        // bitmask (codes within MARGIN of the group min).
        float e2r[2][16];
        #pragma unroll
        for (int i = 0; i < 2; ++i)
            #pragma unroll
            for (int r = 0; r < 16; ++r)
                e2r[i][r] = e2[cb + i * 32 + (r & 3) + 8 * (r >> 2) + 4 * l5];
        #pragma unroll
        for (int j = 0; j < 4; ++j) {
            float m = e2r[0][0] + acc[0][j][0];
            #pragma unroll
            for (int r = 1; r < 16; ++r) m = fminf(m, e2r[0][r] + acc[0][j][r]);
            #pragma unroll
            for (int r = 0; r < 16; ++r) m = fminf(m, e2r[1][r] + acc[1][j][r]);
            m = fminf(m, __shfl_xor(m, 32));   // fold the two l5 halves
            const float th = m + MARGIN;
            unsigned mk[2];
            #pragma unroll
            for (int i = 0; i < 2; ++i) {
                unsigned mm = 0;
                #pragma unroll
                for (int r = 0; r < 16; ++r) {
                    const int row = (r & 3) + 8 * (r >> 2) + 4 * l5;
                    mm |= (e2r[i][r] + acc[i][j][r] <= th) ? (1u << row) : 0u;
                }
                mk[i] = mm | (unsigned)__shfl_xor((int)mm, 32);
            }
            if (l5 == 0) {
                const size_t pt = (size_t)(n0 + j * 32 + c32);
                tminv[pt * 256 + (cb >> 6)] = m;
                tmask[pt * 256 + (cb >> 6)] = ((u64)mk[1] << 32) | (u64)mk[0];
            }
        }
    }
}

// ---------------------------------------------------------------------------
// Rescore: m1 = min over 256 group-mins; for groups with gmin <= m1 + MARGIN,
// read the candidate bitmask and exact-fp32 rescore ONLY those codes, each as
// one coalesced 1KB row load + butterfly dot-reduce. Tie -> lowest j.
// Emits idxf + total_idx. Zeroes loss.
// ---------------------------------------------------------------------------
__global__ __launch_bounds__(256) void rescore(
    const float* __restrict__ tminv, const u64* __restrict__ tmask,
    const float* __restrict__ Zf32, const float* __restrict__ emb,
    const float* __restrict__ e2, int* __restrict__ idxf,
    float* __restrict__ out_idx, float* __restrict__ loss) {
    const int tid = threadIdx.x, lane = tid & 63, w = tid >> 6;
    const int n = blockIdx.x * 4 + w;
    if (blockIdx.x == 0 && tid == 0) loss[0] = 0.f;

    const float4 zr = *(const float4*)(Zf32 + (size_t)n * D + lane * 4);
    const float4 tv = *(const float4*)(tminv + (size_t)n * 256 + lane * 4);

    float m1 = fminf(fminf(tv.x, tv.y), fminf(tv.z, tv.w));
    #pragma unroll
    for (int st = 1; st < 64; st <<= 1) m1 = fminf(m1, __shfl_xor(m1, st));
    const float thresh = m1 + MARGIN;

    u64 best = ~0ull;
    const float tva[4] = {tv.x, tv.y, tv.z, tv.w};
    #pragma unroll
    for (int k = 0; k < 4; ++k) {
        u64 gm = __ballot(tva[k] <= thresh);
        while (gm) {
            const int bit = (int)__builtin_ctzll(gm);
            gm &= gm - 1;
            const int g = bit * 4 + k;                 // 64-code group id
            u64 cm = tmask[(size_t)n * 256 + g];       // uniform broadcast
            while (cm) {
                const int r = (int)__builtin_ctzll(cm);
                cm &= cm - 1;
                const int c = g * 64 + r;
                const float4 ev = *(const float4*)(emb + (size_t)c * D + lane * 4);
                float s = zr.x * ev.x + zr.y * ev.y + zr.z * ev.z + zr.w * ev.w;
                #pragma unroll
                for (int st = 1; st < 64; st <<= 1) s += __shfl_xor(s, st);
                const float d = e2[c] - 2.0f * s;
                unsigned int u = __float_as_uint(d);
                u = (u & 0x80000000u) ? ~u : (u | 0x80000000u);
                const u64 key = ((u64)u << 32) | (unsigned int)c;
                if (key < best) best = key;            // same on all lanes
            }
        }
    }
    if (lane == 0) {
        const int bi = (int)(unsigned int)(best & 0xFFFFFFFFull);
        idxf[n] = bi;
        const int b = n >> 10, hw = n & 1023;
        const float fv = (float)bi;
        #pragma unroll
        for (int sc = 0; sc < 4; ++sc) out_idx[b * 4096 + sc * 1024 + hw] = fv;
    }
}

// ---------------------------------------------------------------------------
// Gather q = emb[idx]; z_hat_out = z + (4q - z); loss accumulation.
// 1024 blocks: (4 c-tiles of 64) x (8 b x 32 hw-tiles). 256 thr = 32 hw x 8 cg.
// ---------------------------------------------------------------------------
__global__ __launch_bounds__(256) void quant_loss(
    const float* __restrict__ z, const float* __restrict__ emb,
    const int* __restrict__ idxf, float* __restrict__ out,
    float* __restrict__ loss) {
    __shared__ int idx_l[32];
    __shared__ float wsum[4];
    const int blk = blockIdx.x;
    const int c0 = (blk >> 8) * 64;
    const int rem = blk & 255;
    const int b = rem >> 5, hw0 = (rem & 31) * 32;
    const int t = threadIdx.x, hw_l = t & 31, cg = t >> 5;
    if (t < 32) idx_l[t] = idxf[b * 1024 + hw0 + t];
    __syncthreads();
    const int j = idx_l[hw_l];
    const float* er = emb + (size_t)j * D + c0 + cg * 8;
    const float4 q0 = *(const float4*)er;
    const float4 q1 = *(const float4*)(er + 4);
    const float qv[8] = {q0.x, q0.y, q0.z, q0.w, q1.x, q1.y, q1.z, q1.w};
    float e = 0.f;
    #pragma unroll
    for (int cc = 0; cc < 8; ++cc) {
        const int c = c0 + cg * 8 + cc;
        const size_t zi = (size_t)b * 262144 + (size_t)c * 1024 + hw0 + hw_l;
        const float zv = z[zi];
        const float q = qv[cc];
        const float zh = ((q + q) + q) + q;   // mimic 4-step accumulation
        out[zi] = zv + (zh - zv);
        e += 30.0f * q * q - 20.0f * q * zv + 4.0f * zv * zv;
    }
    #pragma unroll
    for (int off = 32; off > 0; off >>= 1) e += __shfl_down(e, off);
    if ((t & 63) == 0) wsum[t >> 6] = e;
    __syncthreads();
    if (t == 0) {
        const float s = wsum[0] + wsum[1] + wsum[2] + wsum[3];
        atomicAdd(loss, s * (0.3125f / 2097152.0f));
    }
}

// ---------------------------------------------------------------------------
extern "C" void kernel_launch(void* const* d_in, const int* in_sizes, int n_in,
                              void* d_out, int out_size, void* d_ws, size_t ws_size,
                              hipStream_t stream) {
    const float* z = (const float*)d_in[0];     // [8,256,32,32]
    const float* emb = (const float*)d_in[1];   // [16384,256]
    float* out = (float*)d_out;                 // z_hat_out | loss | total_idx

    // Workspace (~44.1 MB)
    unsigned short* Zpk = (unsigned short*)d_ws;            // 8192*256 bf16
    unsigned short* Epk = Zpk + (size_t)NPTS * D;           // 16384*256 bf16
    float* Zf32 = (float*)(Epk + (size_t)N_E * D);          // 8192*256 f32
    float* e2 = Zf32 + (size_t)NPTS * D;                    // 16384 f32
    float* tminv = e2 + N_E;                                // 8192*256 f32 [pt][g]
    u64* tmask = (u64*)(tminv + (size_t)NPTS * 256);        // 8192*256 u64 [pt][g]
    int* idxf = (int*)(tmask + (size_t)NPTS * 256);         // 8192 i32

    float* loss = out + ZOUT;
    float* out_idx = out + ZOUT + 1;

    prep<<<768, 256, 0, stream>>>(z, emb, Zpk, Zf32, Epk, e2);
    mfma_gemm<<<dim3(NPTS / 128, N_E / (256 * STRIPS)), 256, 0, stream>>>(
        Epk, Zpk, e2, tminv, tmask);
    rescore<<<NPTS / 4, 256, 0, stream>>>(tminv, tmask, Zf32, emb, e2, idxf,
                                          out_idx, loss);
    quant_loss<<<1024, 256, 0, stream>>>(z, emb, idxf, out, loss);
}

// Round 7
// 161.894 us; speedup vs baseline: 1.9825x; 1.9825x over previous
//
#include <hip/hip_runtime.h>

// Problem constants (fixed by the reference).
#define D      256        // vq_embed_dim == C
#define N_E    16384      // codebook size
#define NPTS   8192       // B*H*W
#define ZOUT   2097152    // elements of z_hat_out
#define MARGIN 2.0e-2f    // candidate window; bf16-hi GEMM d-error ~7 sigma
#define STRIPS 4          // 256-code strips per block

typedef short bf16x8 __attribute__((ext_vector_type(8)));
typedef unsigned short us8 __attribute__((ext_vector_type(8)));
typedef float f32x16 __attribute__((ext_vector_type(16)));
typedef unsigned long long u64;

__device__ __forceinline__ unsigned short f2bf(float x) {  // RNE
    unsigned int u = __float_as_uint(x);
    return (unsigned short)((u + 0x7FFFu + ((u >> 16) & 1u)) >> 16);
}
__device__ __forceinline__ void gl_lds16(const void* g, void* l) {
    __builtin_amdgcn_global_load_lds(
        (const __attribute__((address_space(1))) unsigned int*)g,
        (__attribute__((address_space(3))) unsigned int*)l, 16, 0, 0);
}

// ---------------------------------------------------------------------------
// Fused prep. Blocks [0,256): z (32 points each). Blocks [256,768): emb
// (32 codes each). Zpk = bf16(-2z), Epk = bf16(emb), both in MFMA fragment-
// chunk layout (chunk (g,ks): 64 lanes x 16B, lane l = (row&31)+((k>>3)&1)*32).
// Zf32 = z transposed to [n][k]. e2[j] = |emb_j|^2 fp32.
// Also zeroes loss (must complete before rescore_quant's atomicAdds).
// ---------------------------------------------------------------------------
__global__ __launch_bounds__(256) void prep(
    const float* __restrict__ z, const float* __restrict__ emb,
    unsigned short* __restrict__ Zpk, float* __restrict__ Zf32,
    unsigned short* __restrict__ Epk, float* __restrict__ e2,
    float* __restrict__ loss) {
    const int t = threadIdx.x;
    if (blockIdx.x == 0 && t == 0) loss[0] = 0.f;
    if (blockIdx.x < 256) {
        const int n0 = blockIdx.x * 32;
        const int p = t & 31, ks8 = t >> 5;     // 8 k-slabs of 32
        const int n = n0 + p;
        const int b = n >> 10, hw = n & 1023;
        const float* zb = z + (size_t)b * 262144 + hw;
        const int k0 = ks8 * 32;
        float v[32];
        #pragma unroll
        for (int kk = 0; kk < 32; ++kk)
            v[kk] = zb[(size_t)(k0 + kk) * 1024];   // coalesced in p
        #pragma unroll
        for (int i = 0; i < 8; ++i) {
            float4 f = {v[i * 4], v[i * 4 + 1], v[i * 4 + 2], v[i * 4 + 3]};
            *(float4*)(Zf32 + (size_t)n * D + k0 + i * 4) = f;
        }
        const int g = n >> 5;
        #pragma unroll
        for (int i = 0; i < 4; ++i) {               // 4 us8 per 32-k slab
            us8 hv;
            #pragma unroll
            for (int c = 0; c < 8; ++c) hv[c] = f2bf(-2.0f * v[i * 8 + c]);
            const int kabs = k0 + i * 8;
            const int ks = kabs >> 4;
            const int l = (n & 31) + ((kabs >> 3) & 1) * 32;
            *(us8*)(Zpk + ((size_t)(g * 16 + ks) * 64 + l) * 8) = hv;
        }
    } else {
        const int j0 = (blockIdx.x - 256) * 32;
        const int jj = j0 + (t >> 3), q = t & 7;    // 8 k-slabs of 32
        const float* row = emb + (size_t)jj * D + q * 32;
        float v[32];
        float s = 0.f;
        #pragma unroll
        for (int i = 0; i < 8; ++i) {
            const float4 x = *(const float4*)(row + i * 4);
            v[i * 4] = x.x; v[i * 4 + 1] = x.y; v[i * 4 + 2] = x.z; v[i * 4 + 3] = x.w;
            s += x.x * x.x + x.y * x.y + x.z * x.z + x.w * x.w;
        }
        const int g = jj >> 5;
        #pragma unroll
        for (int i = 0; i < 4; ++i) {
            us8 hv;
            #pragma unroll
            for (int c = 0; c < 8; ++c) hv[c] = f2bf(v[i * 8 + c]);
            const int kabs = q * 32 + i * 8;
            const int ks = kabs >> 4;
            const int l = (jj & 31) + ((kabs >> 3) & 1) * 32;
            *(us8*)(Epk + ((size_t)(g * 16 + ks) * 64 + l) * 8) = hv;
        }
        s += __shfl_xor(s, 1);
        s += __shfl_xor(s, 2);
        s += __shfl_xor(s, 4);
        if (q == 0) e2[jj] = s;
    }
}

// ---------------------------------------------------------------------------
// GEMM + group-min + candidate mask. ROUND-1 PROVEN BODY — do not touch:
// depth-1 register prefetch, #pragma unroll 4, [pt][g] stores. (Depth-2 /
// cross-strip preload / full unroll spill to scratch: FETCH 37->468 MB,
// gemm 83->225 us, rounds 5-6. Manual XCD swizzle also catastrophic, r5.)
// Block: 128 points (LDS, staged once) x STRIPS*256 codes. 4 waves; wave wid
// owns a DISTINCT 64-code column, all 128 points. Wave frags: 2 code x 4
// point of 32x32x16; ef from global, pf from LDS; ks+1 register prefetch.
// d~ = e2[code] + acc (Zpk holds -2z). Per (point, 64-code group) emits:
//   tminv[pt][g] = min over 64 codes
//   tmask[pt][g] = bitmask of codes with d~ <= min+MARGIN
// ---------------------------------------------------------------------------
__global__ __launch_bounds__(256, 2) void mfma_gemm(
    const unsigned short* __restrict__ Epk, const unsigned short* __restrict__ Zpk,
    const float* __restrict__ e2, float* __restrict__ tminv,
    u64* __restrict__ tmask) {
    __shared__ unsigned short Zbuf[64 * 512];   // 64 KB

    const int tid = threadIdx.x, lane = tid & 63, wid = tid >> 6;
    const int c32 = lane & 31, l5 = lane >> 5;
    const int n0 = blockIdx.x * 128;
    const int cs0 = blockIdx.y * (STRIPS * 256);

    #pragma unroll
    for (int ks = 0; ks < 16; ++ks)
        gl_lds16(Zpk + ((size_t)((n0 >> 5) + wid) * 16 + ks) * 512 + lane * 8,
                 Zbuf + (wid * 16 + ks) * 512);
    __syncthreads();   // single drain per block

    for (int s = 0; s < STRIPS; ++s) {
        const int cb = cs0 + s * 256 + wid * 64;   // this wave's 64 codes
        const unsigned short* eb = Epk + ((size_t)(cb >> 5) * 16) * 512 + lane * 8;
        const unsigned short* zb = Zbuf + lane * 8;

        f32x16 acc[2][4];
        const f32x16 z16 = {0.f};
        #pragma unroll
        for (int i = 0; i < 2; ++i)
            #pragma unroll
            for (int j = 0; j < 4; ++j) acc[i][j] = z16;

        bf16x8 ec[2], pc[4];
        ec[0] = *(const bf16x8*)(eb);
        ec[1] = *(const bf16x8*)(eb + 16 * 512);
        #pragma unroll
        for (int j = 0; j < 4; ++j) pc[j] = *(const bf16x8*)(zb + (j * 16) * 512);

        #pragma unroll 4
        for (int ks = 0; ks < 16; ++ks) {
            bf16x8 en[2], pn[4];
            if (ks < 15) {
                en[0] = *(const bf16x8*)(eb + (ks + 1) * 512);
                en[1] = *(const bf16x8*)(eb + (16 + ks + 1) * 512);
                #pragma unroll
                for (int j = 0; j < 4; ++j)
                    pn[j] = *(const bf16x8*)(zb + (j * 16 + ks + 1) * 512);
            }
            #pragma unroll
            for (int i = 0; i < 2; ++i)
                #pragma unroll
                for (int j = 0; j < 4; ++j)
                    acc[i][j] = __builtin_amdgcn_mfma_f32_32x32x16_bf16(
                        ec[i], pc[j], acc[i][j], 0, 0, 0);
            if (ks < 15) {
                ec[0] = en[0]; ec[1] = en[1];
                #pragma unroll
                for (int j = 0; j < 4; ++j) pc[j] = pn[j];
            }
        }

        // Epilogue: per point-lane, min over the wave's 64 codes + candidate
        // bitmask (codes within MARGIN of the group min).
        float e2r[2][16];
        #pragma unroll
        for (int i = 0; i < 2; ++i)
            #pragma unroll
            for (int r = 0; r < 16; ++r)
                e2r[i][r] = e2[cb + i * 32 + (r & 3) + 8 * (r >> 2) + 4 * l5];
        #pragma unroll
        for (int j = 0; j < 4; ++j) {
            float m = e2r[0][0] + acc[0][j][0];
            #pragma unroll
            for (int r = 1; r < 16; ++r) m = fminf(m, e2r[0][r] + acc[0][j][r]);
            #pragma unroll
            for (int r = 0; r < 16; ++r) m = fminf(m, e2r[1][r] + acc[1][j][r]);
            m = fminf(m, __shfl_xor(m, 32));   // fold the two l5 halves
            const float th = m + MARGIN;
            unsigned mk[2];
            #pragma unroll
            for (int i = 0; i < 2; ++i) {
                unsigned mm = 0;
                #pragma unroll
                for (int r = 0; r < 16; ++r) {
                    const int row = (r & 3) + 8 * (r >> 2) + 4 * l5;
                    mm |= (e2r[i][r] + acc[i][j][r] <= th) ? (1u << row) : 0u;
                }
                mk[i] = mm | (unsigned)__shfl_xor((int)mm, 32);
            }
            if (l5 == 0) {
                const size_t pt = (size_t)(n0 + j * 32 + c32);
                tminv[pt * 256 + (cb >> 6)] = m;
                tmask[pt * 256 + (cb >> 6)] = ((u64)mk[1] << 32) | (u64)mk[0];
            }
        }
    }
}

// ---------------------------------------------------------------------------
// Fused rescore + quantize/loss. 256 blocks x 1024 thr; block = 32
// consecutive points (one b, hw0..hw0+31).
// Phase 1 (round-1 rescore body, 16 waves x 2 serial points): m1 = min over
// 256 group-mins; for groups with gmin <= m1+MARGIN read candidate bitmask,
// exact-fp32 rescore those codes (coalesced 1KB row + butterfly). Tie ->
// lowest j. Winner index -> LDS (no global idxf round-trip).
// Phase 2 (quant_loss body re-tiled): 32 hw x 32 cg x 8 c covers all 256 c;
// z/out accesses are full 128B lines; emb gather L2/L3-resident; block loss
// reduce + one atomicAdd. out_idx written coalesced by threads 0..31.
// ---------------------------------------------------------------------------
__global__ __launch_bounds__(1024) void rescore_quant(
    const float* __restrict__ tminv, const u64* __restrict__ tmask,
    const float* __restrict__ Zf32, const float* __restrict__ emb,
    const float* __restrict__ e2, const float* __restrict__ z,
    float* __restrict__ out, float* __restrict__ out_idx,
    float* __restrict__ loss) {
    __shared__ int idx_s[32];
    __shared__ float wsum[16];
    const int tid = threadIdx.x, lane = tid & 63, wd = tid >> 6;
    const int n0 = blockIdx.x * 32;
    const int b = n0 >> 10, hw0 = n0 & 1023;

    // ---- Phase 1: rescore (each wave: 2 points serially) ----
    #pragma unroll 1
    for (int p = 0; p < 2; ++p) {
        const int lp = wd * 2 + p;
        const int n = n0 + lp;
        const float4 zr = *(const float4*)(Zf32 + (size_t)n * D + lane * 4);
        const float4 tv = *(const float4*)(tminv + (size_t)n * 256 + lane * 4);

        float m1 = fminf(fminf(tv.x, tv.y), fminf(tv.z, tv.w));
        #pragma unroll
        for (int st = 1; st < 64; st <<= 1) m1 = fminf(m1, __shfl_xor(m1, st));
        const float thresh = m1 + MARGIN;

        u64 best = ~0ull;
        const float tva[4] = {tv.x, tv.y, tv.z, tv.w};
        #pragma unroll
        for (int k = 0; k < 4; ++k) {
            u64 gm = __ballot(tva[k] <= thresh);
            while (gm) {
                const int bit = (int)__builtin_ctzll(gm);
                gm &= gm - 1;
                const int g = bit * 4 + k;                 // 64-code group id
                u64 cm = tmask[(size_t)n * 256 + g];       // uniform broadcast
                while (cm) {
                    const int r = (int)__builtin_ctzll(cm);
                    cm &= cm - 1;
                    const int c = g * 64 + r;
                    const float4 ev = *(const float4*)(emb + (size_t)c * D + lane * 4);
                    float s = zr.x * ev.x + zr.y * ev.y + zr.z * ev.z + zr.w * ev.w;
                    #pragma unroll
                    for (int st = 1; st < 64; st <<= 1) s += __shfl_xor(s, st);
                    const float d = e2[c] - 2.0f * s;
                    unsigned int u = __float_as_uint(d);
                    u = (u & 0x80000000u) ? ~u : (u | 0x80000000u);
                    const u64 key = ((u64)u << 32) | (unsigned int)c;
                    if (key < best) best = key;            // same on all lanes
                }
            }
        }
        if (lane == 0)
            idx_s[lp] = (int)(unsigned int)(best & 0xFFFFFFFFull);
    }
    __syncthreads();

    // ---- Phase 2: gather + z_hat_out + loss (+ coalesced out_idx) ----
    if (tid < 32) {
        const float fv = (float)idx_s[tid];
        #pragma unroll
        for (int sc = 0; sc < 4; ++sc)
            out_idx[b * 4096 + sc * 1024 + hw0 + tid] = fv;
    }
    const int hw_l = tid & 31, cg = tid >> 5;   // cg in [0,32), 8 c each
    const int j = idx_s[hw_l];
    const float* er = emb + (size_t)j * D + cg * 8;
    const float4 q0 = *(const float4*)er;
    const float4 q1 = *(const float4*)(er + 4);
    const float qv[8] = {q0.x, q0.y, q0.z, q0.w, q1.x, q1.y, q1.z, q1.w};
    float e = 0.f;
    #pragma unroll
    for (int cc = 0; cc < 8; ++cc) {
        const int c = cg * 8 + cc;
        const size_t zi = (size_t)b * 262144 + (size_t)c * 1024 + hw0 + hw_l;
        const float zv = z[zi];
        const float q = qv[cc];
        const float zh = ((q + q) + q) + q;   // mimic 4-step accumulation
        out[zi] = zv + (zh - zv);
        e += 30.0f * q * q - 20.0f * q * zv + 4.0f * zv * zv;
    }
    #pragma unroll
    for (int off = 32; off > 0; off >>= 1) e += __shfl_down(e, off);
    if (lane == 0) wsum[wd] = e;
    __syncthreads();
    if (tid == 0) {
        float s = 0.f;
        #pragma unroll
        for (int i = 0; i < 16; ++i) s += wsum[i];
        atomicAdd(loss, s * (0.3125f / 2097152.0f));
    }
}

// ---------------------------------------------------------------------------
extern "C" void kernel_launch(void* const* d_in, const int* in_sizes, int n_in,
                              void* d_out, int out_size, void* d_ws, size_t ws_size,
                              hipStream_t stream) {
    const float* z = (const float*)d_in[0];     // [8,256,32,32]
    const float* emb = (const float*)d_in[1];   // [16384,256]
    float* out = (float*)d_out;                 // z_hat_out | loss | total_idx

    // Workspace (~44 MB)
    unsigned short* Zpk = (unsigned short*)d_ws;            // 8192*256 bf16
    unsigned short* Epk = Zpk + (size_t)NPTS * D;           // 16384*256 bf16
    float* Zf32 = (float*)(Epk + (size_t)N_E * D);          // 8192*256 f32
    float* e2 = Zf32 + (size_t)NPTS * D;                    // 16384 f32
    float* tminv = e2 + N_E;                                // 8192*256 f32 [pt][g]
    u64* tmask = (u64*)(tminv + (size_t)NPTS * 256);        // 8192*256 u64 [pt][g]

    float* loss = out + ZOUT;
    float* out_idx = out + ZOUT + 1;

    prep<<<768, 256, 0, stream>>>(z, emb, Zpk, Zf32, Epk, e2, loss);
    mfma_gemm<<<dim3(NPTS / 128, N_E / (256 * STRIPS)), 256, 0, stream>>>(
        Epk, Zpk, e2, tminv, tmask);
    rescore_quant<<<256, 1024, 0, stream>>>(tminv, tmask, Zf32, emb, e2, z,
                                            out, out_idx, loss);
}

// Round 8
// 161.556 us; speedup vs baseline: 1.9867x; 1.0021x over previous
//
#include <hip/hip_runtime.h>

// Problem constants (fixed by the reference).
#define D      256        // vq_embed_dim == C
#define N_E    16384      // codebook size
#define NPTS   8192       // B*H*W
#define ZOUT   2097152    // elements of z_hat_out
#define MARGIN 2.0e-2f    // candidate window; bf16-hi GEMM d-error ~7 sigma
#define STRIPS 4          // 256-code strips per block
#define ECH    17         // Epk chunks per group: 16 K-chunks + 1 e2-fold chunk

typedef short bf16x8 __attribute__((ext_vector_type(8)));
typedef unsigned short us8 __attribute__((ext_vector_type(8)));
typedef float f32x16 __attribute__((ext_vector_type(16)));
typedef unsigned long long u64;

__device__ __forceinline__ unsigned short f2bf(float x) {  // RNE
    unsigned int u = __float_as_uint(x);
    return (unsigned short)((u + 0x7FFFu + ((u >> 16) & 1u)) >> 16);
}
__device__ __forceinline__ float bf2f(unsigned short h) {
    return __uint_as_float((unsigned int)h << 16);
}
__device__ __forceinline__ void gl_lds16(const void* g, void* l) {
    __builtin_amdgcn_global_load_lds(
        (const __attribute__((address_space(1))) unsigned int*)g,
        (__attribute__((address_space(3))) unsigned int*)l, 16, 0, 0);
}

// ---------------------------------------------------------------------------
// Fused prep. Blocks [0,256): z (32 points each). Blocks [256,768): emb
// (32 codes each). Zpk = bf16(-2z) (16 chunks/group), Epk = bf16(emb)
// (ECH=17 chunks/group: chunk 16 holds the e2 hi/lo A-fragment so the GEMM
// folds +e2 with one peeled MFMA — construction verified in round 2).
// Fragment chunk (g,ks): 64 lanes x 16B, lane l = (row&31)+((k>>3)&1)*32.
// Zf32 = z transposed to [n][k]. e2[j] = |emb_j|^2 fp32 (rescore needs it).
// Also zeroes loss (must complete before rescore_quant's atomicAdds).
// ---------------------------------------------------------------------------
__global__ __launch_bounds__(256) void prep(
    const float* __restrict__ z, const float* __restrict__ emb,
    unsigned short* __restrict__ Zpk, float* __restrict__ Zf32,
    unsigned short* __restrict__ Epk, float* __restrict__ e2,
    float* __restrict__ loss) {
    __shared__ float sh[32];
    const int t = threadIdx.x;
    if (blockIdx.x == 0 && t == 0) loss[0] = 0.f;
    if (blockIdx.x < 256) {
        const int n0 = blockIdx.x * 32;
        const int p = t & 31, ks8 = t >> 5;     // 8 k-slabs of 32
        const int n = n0 + p;
        const int b = n >> 10, hw = n & 1023;
        const float* zb = z + (size_t)b * 262144 + hw;
        const int k0 = ks8 * 32;
        float v[32];
        #pragma unroll
        for (int kk = 0; kk < 32; ++kk)
            v[kk] = zb[(size_t)(k0 + kk) * 1024];   // coalesced in p
        #pragma unroll
        for (int i = 0; i < 8; ++i) {
            float4 f = {v[i * 4], v[i * 4 + 1], v[i * 4 + 2], v[i * 4 + 3]};
            *(float4*)(Zf32 + (size_t)n * D + k0 + i * 4) = f;
        }
        const int g = n >> 5;
        #pragma unroll
        for (int i = 0; i < 4; ++i) {               // 4 us8 per 32-k slab
            us8 hv;
            #pragma unroll
            for (int c = 0; c < 8; ++c) hv[c] = f2bf(-2.0f * v[i * 8 + c]);
            const int kabs = k0 + i * 8;
            const int ks = kabs >> 4;
            const int l = (n & 31) + ((kabs >> 3) & 1) * 32;
            *(us8*)(Zpk + ((size_t)(g * 16 + ks) * 64 + l) * 8) = hv;
        }
    } else {
        const int bi = blockIdx.x - 256;            // code group id
        const int j0 = bi * 32;
        const int jj = j0 + (t >> 3), q = t & 7;    // 8 k-slabs of 32
        const float* row = emb + (size_t)jj * D + q * 32;
        float v[32];
        float s = 0.f;
        #pragma unroll
        for (int i = 0; i < 8; ++i) {
            const float4 x = *(const float4*)(row + i * 4);
            v[i * 4] = x.x; v[i * 4 + 1] = x.y; v[i * 4 + 2] = x.z; v[i * 4 + 3] = x.w;
            s += x.x * x.x + x.y * x.y + x.z * x.z + x.w * x.w;
        }
        #pragma unroll
        for (int i = 0; i < 4; ++i) {
            us8 hv;
            #pragma unroll
            for (int c = 0; c < 8; ++c) hv[c] = f2bf(v[i * 8 + c]);
            const int kabs = q * 32 + i * 8;
            const int ks = kabs >> 4;
            const int l = (jj & 31) + ((kabs >> 3) & 1) * 32;
            *(us8*)(Epk + ((size_t)(bi * ECH + ks) * 64 + l) * 8) = hv;
        }
        s += __shfl_xor(s, 1);
        s += __shfl_xor(s, 2);
        s += __shfl_xor(s, 4);
        if (q == 0) { e2[jj] = s; sh[t >> 3] = s; }
        __syncthreads();
        if (t < 64) {   // chunk 16: lane l<32 -> {e2_hi, e2_lo, 0..}; else 0
            us8 hv;
            #pragma unroll
            for (int c = 0; c < 8; ++c) hv[c] = 0;
            if (t < 32) {
                const float vv = sh[t];
                const unsigned short hi = f2bf(vv);
                hv[0] = hi;
                hv[1] = f2bf(vv - bf2f(hi));
            }
            *(us8*)(Epk + ((size_t)bi * ECH + 16) * 512 + t * 8) = hv;
        }
    }
}

// ---------------------------------------------------------------------------
// GEMM + group-min + candidate mask. Round-1 proven skeleton (128 pts x
// STRIPS*256 codes, 4 waves, 2x4 frags of 32x32x16, LDS Z staged once,
// #pragma unroll 4, [pt][g] coalesced stores) with two coupled upgrades:
//  - DEPTH-2 E prefetch via 2-slot parity ring (chunk ks+2 issued into the
//    slot freed at ks) — covers ~2 k-steps of L2 latency vs 1.
//  - e2 folded via Epk chunk 16 (A = e2 hi/lo frag, B = register constant
//    ones frag pu) — one peeled MFMA pass replaces the 32 scattered e2
//    loads + 128 VALU adds of the old epilogue, freeing 32 registers
//    (which is what pays for depth-2 without r5/r6's spill explosion).
// d~ = acc directly. Per (point, 64-code group):
//   tminv[pt][g] = min over 64 codes; tmask[pt][g] = d~ <= min+MARGIN bits.
// Plain dim3(64,16) grid (manual XCD swizzle was catastrophic, r5).
// Spill tripwire: FETCH > 60 MB or dur > 90 us => revert to r7 gemm.
// ---------------------------------------------------------------------------
__global__ __launch_bounds__(256, 2) void mfma_gemm(
    const unsigned short* __restrict__ Epk, const unsigned short* __restrict__ Zpk,
    float* __restrict__ tminv, u64* __restrict__ tmask) {
    __shared__ unsigned short Zbuf[64 * 512];   // 64 KB (Zpk: 16 chunks/group)

    const int tid = threadIdx.x, lane = tid & 63, wid = tid >> 6;
    const int c32 = lane & 31, l5 = lane >> 5;
    const int n0 = blockIdx.x * 128;
    const int cs0 = blockIdx.y * (STRIPS * 256);

    // Ones B-fragment for the e2 fold: k-slots 0,1 = 1.0 (l5==0 lanes).
    us8 puu;
    #pragma unroll
    for (int c = 0; c < 8; ++c) puu[c] = 0;
    if (l5 == 0) { puu[0] = 0x3F80; puu[1] = 0x3F80; }
    const bf16x8 pu = (bf16x8)puu;

    #pragma unroll
    for (int ks = 0; ks < 16; ++ks)
        gl_lds16(Zpk + ((size_t)((n0 >> 5) + wid) * 16 + ks) * 512 + lane * 8,
                 Zbuf + (wid * 16 + ks) * 512);
    __syncthreads();   // single drain per block

    for (int s = 0; s < STRIPS; ++s) {
        const int cb = cs0 + s * 256 + wid * 64;   // this wave's 64 codes
        const unsigned short* eb =
            Epk + ((size_t)(cb >> 5) * ECH) * 512 + lane * 8;
        const unsigned short* zb = Zbuf + lane * 8;

        f32x16 acc[2][4];
        const f32x16 z16 = {0.f};
        #pragma unroll
        for (int i = 0; i < 2; ++i)
            #pragma unroll
            for (int j = 0; j < 4; ++j) acc[i][j] = z16;

        // Depth-2 E parity ring: eq0 = even chunks, eq1 = odd chunks.
        bf16x8 eq0a = *(const bf16x8*)(eb);                       // chunk 0
        bf16x8 eq0b = *(const bf16x8*)(eb + ECH * 512);
        bf16x8 eq1a = *(const bf16x8*)(eb + 512);                 // chunk 1
        bf16x8 eq1b = *(const bf16x8*)(eb + ECH * 512 + 512);
        bf16x8 pc[4], pn[4];
        #pragma unroll
        for (int j = 0; j < 4; ++j) pc[j] = *(const bf16x8*)(zb + (j * 16) * 512);

        #pragma unroll 4
        for (int ks = 0; ks < 16; ++ks) {
            bf16x8 ef0, ef1;
            if ((ks & 1) == 0) { ef0 = eq0a; ef1 = eq0b; }
            else               { ef0 = eq1a; ef1 = eq1b; }
            if (ks < 15) {      // issue chunk ks+2 (<=16) into the freed slot
                const unsigned short* ep = eb + (ks + 2) * 512;
                if ((ks & 1) == 0) {
                    eq0a = *(const bf16x8*)ep;
                    eq0b = *(const bf16x8*)(ep + ECH * 512);
                } else {
                    eq1a = *(const bf16x8*)ep;
                    eq1b = *(const bf16x8*)(ep + ECH * 512);
                }
                #pragma unroll
                for (int j = 0; j < 4; ++j)
                    pn[j] = *(const bf16x8*)(zb + (j * 16 + ks + 1) * 512);
            }
            acc[0][0] = __builtin_amdgcn_mfma_f32_32x32x16_bf16(ef0, pc[0], acc[0][0], 0, 0, 0);
            acc[0][1] = __builtin_amdgcn_mfma_f32_32x32x16_bf16(ef0, pc[1], acc[0][1], 0, 0, 0);
            acc[0][2] = __builtin_amdgcn_mfma_f32_32x32x16_bf16(ef0, pc[2], acc[0][2], 0, 0, 0);
            acc[0][3] = __builtin_amdgcn_mfma_f32_32x32x16_bf16(ef0, pc[3], acc[0][3], 0, 0, 0);
            acc[1][0] = __builtin_amdgcn_mfma_f32_32x32x16_bf16(ef1, pc[0], acc[1][0], 0, 0, 0);
            acc[1][1] = __builtin_amdgcn_mfma_f32_32x32x16_bf16(ef1, pc[1], acc[1][1], 0, 0, 0);
            acc[1][2] = __builtin_amdgcn_mfma_f32_32x32x16_bf16(ef1, pc[2], acc[1][2], 0, 0, 0);
            acc[1][3] = __builtin_amdgcn_mfma_f32_32x32x16_bf16(ef1, pc[3], acc[1][3], 0, 0, 0);
            if (ks < 15) {
                #pragma unroll
                for (int j = 0; j < 4; ++j) pc[j] = pn[j];
            }
        }
        // e2 fold: chunk 16 arrived in eq0 (loaded at ks=14). acc becomes d~.
        #pragma unroll
        for (int j = 0; j < 4; ++j) {
            acc[0][j] = __builtin_amdgcn_mfma_f32_32x32x16_bf16(eq0a, pu, acc[0][j], 0, 0, 0);
            acc[1][j] = __builtin_amdgcn_mfma_f32_32x32x16_bf16(eq0b, pu, acc[1][j], 0, 0, 0);
        }

        // Epilogue: per point-lane, min over the wave's 64 codes + candidate
        // bitmask (codes within MARGIN of the group min). No e2 gathers.
        #pragma unroll
        for (int j = 0; j < 4; ++j) {
            float m = acc[0][j][0];
            #pragma unroll
            for (int r = 1; r < 16; ++r) m = fminf(m, acc[0][j][r]);
            #pragma unroll
            for (int r = 0; r < 16; ++r) m = fminf(m, acc[1][j][r]);
            m = fminf(m, __shfl_xor(m, 32));   // fold the two l5 halves
            const float th = m + MARGIN;
            unsigned mk[2];
            #pragma unroll
            for (int i = 0; i < 2; ++i) {
                unsigned mm = 0;
                #pragma unroll
                for (int r = 0; r < 16; ++r) {
                    const int row = (r & 3) + 8 * (r >> 2) + 4 * l5;
                    mm |= (acc[i][j][r] <= th) ? (1u << row) : 0u;
                }
                mk[i] = mm | (unsigned)__shfl_xor((int)mm, 32);
            }
            if (l5 == 0) {
                const size_t pt = (size_t)(n0 + j * 32 + c32);
                tminv[pt * 256 + (cb >> 6)] = m;
                tmask[pt * 256 + (cb >> 6)] = ((u64)mk[1] << 32) | (u64)mk[0];
            }
        }
    }
}

// ---------------------------------------------------------------------------
// Fused rescore + quantize/loss (round-7 proven). 256 blocks x 1024 thr;
// block = 32 consecutive points (one b, hw0..hw0+31).
// Phase 1: per point m1 = min over 256 group-mins; for groups with gmin <=
// m1+MARGIN read candidate bitmask, exact-fp32 rescore those codes (coalesced
// 1KB row + butterfly). Tie -> lowest j. Winner index -> LDS.
// Phase 2: gather + z_hat_out + loss; full 128B lines; one atomicAdd.
// ---------------------------------------------------------------------------
__global__ __launch_bounds__(1024) void rescore_quant(
    const float* __restrict__ tminv, const u64* __restrict__ tmask,
    const float* __restrict__ Zf32, const float* __restrict__ emb,
    const float* __restrict__ e2, const float* __restrict__ z,
    float* __restrict__ out, float* __restrict__ out_idx,
    float* __restrict__ loss) {
    __shared__ int idx_s[32];
    __shared__ float wsum[16];
    const int tid = threadIdx.x, lane = tid & 63, wd = tid >> 6;
    const int n0 = blockIdx.x * 32;
    const int b = n0 >> 10, hw0 = n0 & 1023;

    // ---- Phase 1: rescore (each wave: 2 points serially) ----
    #pragma unroll 1
    for (int p = 0; p < 2; ++p) {
        const int lp = wd * 2 + p;
        const int n = n0 + lp;
        const float4 zr = *(const float4*)(Zf32 + (size_t)n * D + lane * 4);
        const float4 tv = *(const float4*)(tminv + (size_t)n * 256 + lane * 4);

        float m1 = fminf(fminf(tv.x, tv.y), fminf(tv.z, tv.w));
        #pragma unroll
        for (int st = 1; st < 64; st <<= 1) m1 = fminf(m1, __shfl_xor(m1, st));
        const float thresh = m1 + MARGIN;

        u64 best = ~0ull;
        const float tva[4] = {tv.x, tv.y, tv.z, tv.w};
        #pragma unroll
        for (int k = 0; k < 4; ++k) {
            u64 gm = __ballot(tva[k] <= thresh);
            while (gm) {
                const int bit = (int)__builtin_ctzll(gm);
                gm &= gm - 1;
                const int g = bit * 4 + k;                 // 64-code group id
                u64 cm = tmask[(size_t)n * 256 + g];       // uniform broadcast
                while (cm) {
                    const int r = (int)__builtin_ctzll(cm);
                    cm &= cm - 1;
                    const int c = g * 64 + r;
                    const float4 ev = *(const float4*)(emb + (size_t)c * D + lane * 4);
                    float s = zr.x * ev.x + zr.y * ev.y + zr.z * ev.z + zr.w * ev.w;
                    #pragma unroll
                    for (int st = 1; st < 64; st <<= 1) s += __shfl_xor(s, st);
                    const float d = e2[c] - 2.0f * s;
                    unsigned int u = __float_as_uint(d);
                    u = (u & 0x80000000u) ? ~u : (u | 0x80000000u);
                    const u64 key = ((u64)u << 32) | (unsigned int)c;
                    if (key < best) best = key;            // same on all lanes
                }
            }
        }
        if (lane == 0)
            idx_s[lp] = (int)(unsigned int)(best & 0xFFFFFFFFull);
    }
    __syncthreads();

    // ---- Phase 2: gather + z_hat_out + loss (+ coalesced out_idx) ----
    if (tid < 32) {
        const float fv = (float)idx_s[tid];
        #pragma unroll
        for (int sc = 0; sc < 4; ++sc)
            out_idx[b * 4096 + sc * 1024 + hw0 + tid] = fv;
    }
    const int hw_l = tid & 31, cg = tid >> 5;   // cg in [0,32), 8 c each
    const int j = idx_s[hw_l];
    const float* er = emb + (size_t)j * D + cg * 8;
    const float4 q0 = *(const float4*)er;
    const float4 q1 = *(const float4*)(er + 4);
    const float qv[8] = {q0.x, q0.y, q0.z, q0.w, q1.x, q1.y, q1.z, q1.w};
    float e = 0.f;
    #pragma unroll
    for (int cc = 0; cc < 8; ++cc) {
        const int c = cg * 8 + cc;
        const size_t zi = (size_t)b * 262144 + (size_t)c * 1024 + hw0 + hw_l;
        const float zv = z[zi];
        const float q = qv[cc];
        const float zh = ((q + q) + q) + q;   // mimic 4-step accumulation
        out[zi] = zv + (zh - zv);
        e += 30.0f * q * q - 20.0f * q * zv + 4.0f * zv * zv;
    }
    #pragma unroll
    for (int off = 32; off > 0; off >>= 1) e += __shfl_down(e, off);
    if (lane == 0) wsum[wd] = e;
    __syncthreads();
    if (tid == 0) {
        float s = 0.f;
        #pragma unroll
        for (int i = 0; i < 16; ++i) s += wsum[i];
        atomicAdd(loss, s * (0.3125f / 2097152.0f));
    }
}

// ---------------------------------------------------------------------------
extern "C" void kernel_launch(void* const* d_in, const int* in_sizes, int n_in,
                              void* d_out, int out_size, void* d_ws, size_t ws_size,
                              hipStream_t stream) {
    const float* z = (const float*)d_in[0];     // [8,256,32,32]
    const float* emb = (const float*)d_in[1];   // [16384,256]
    float* out = (float*)d_out;                 // z_hat_out | loss | total_idx

    // Workspace (~45 MB)
    unsigned short* Zpk = (unsigned short*)d_ws;            // 8192*256 bf16
    unsigned short* Epk = Zpk + (size_t)NPTS * D;           // 512 groups * 17 * 512
    float* Zf32 = (float*)(Epk + (size_t)(N_E / 32) * ECH * 512);
    float* e2 = Zf32 + (size_t)NPTS * D;                    // 16384 f32
    float* tminv = e2 + N_E;                                // 8192*256 f32 [pt][g]
    u64* tmask = (u64*)(tminv + (size_t)NPTS * 256);        // 8192*256 u64 [pt][g]

    float* loss = out + ZOUT;
    float* out_idx = out + ZOUT + 1;

    prep<<<768, 256, 0, stream>>>(z, emb, Zpk, Zf32, Epk, e2, loss);
    mfma_gemm<<<dim3(NPTS / 128, N_E / (256 * STRIPS)), 256, 0, stream>>>(
        Epk, Zpk, tminv, tmask);
    rescore_quant<<<256, 1024, 0, stream>>>(tminv, tmask, Zf32, emb, e2, z,
                                            out, out_idx, loss);
}